// Round 16
// baseline (2179.788 us; speedup 1.0000x reference)
//
#include <hip/hip_runtime.h>
#include <hip/hip_cooperative_groups.h>
#include <hip/hip_fp16.h>
#include <cmath>

namespace cg = cooperative_groups;

#define H 128
#define GAMMA 0.1f
#define EPS 0.1f
#define NEG 0.01f
#define NGRAPH 256
#define GRID 512     // cooperative grid: 2 blocks/CU co-resident

typedef _Float16 half_t;
typedef _Float16 f16x8 __attribute__((ext_vector_type(8)));
typedef _Float16 f16x2 __attribute__((ext_vector_type(2)));
typedef float f32x4 __attribute__((ext_vector_type(4)));

__device__ __forceinline__ float fast_tanh(float v) {
    float e = __builtin_amdgcn_exp2f(v * 2.8853900817779268f);
    float r = __builtin_amdgcn_rcpf(e + 1.0f);
    return 1.0f - 2.0f * r;
}

// ---------- shared device bodies (used by both mega and fallback kernels) ----

__device__ __forceinline__ void gather_node(const half_t* cur,
        const int* row_start, const int* csr_src, half_t* xaggh,
        int node, int lane) {
    int begin = row_start[node];
    int end   = row_start[node + 1];
    f16x2 accA = (f16x2){(half_t)0.f, (half_t)0.f};
    f16x2 accB = (f16x2){(half_t)0.f, (half_t)0.f};
    for (int eb = begin; eb < end; eb += 64) {
        int cnt = min(64, end - eb);
        int myidx = csr_src[eb + min(lane, cnt - 1)];
        int j = 0;
        for (; j + 7 < cnt; j += 8) {
            int s0 = __builtin_amdgcn_readlane(myidx, j + 0);
            int s1 = __builtin_amdgcn_readlane(myidx, j + 1);
            int s2 = __builtin_amdgcn_readlane(myidx, j + 2);
            int s3 = __builtin_amdgcn_readlane(myidx, j + 3);
            int s4 = __builtin_amdgcn_readlane(myidx, j + 4);
            int s5 = __builtin_amdgcn_readlane(myidx, j + 5);
            int s6 = __builtin_amdgcn_readlane(myidx, j + 6);
            int s7 = __builtin_amdgcn_readlane(myidx, j + 7);
            f16x2 v0 = *(const f16x2*)(cur + (size_t)s0 * H + lane * 2);
            f16x2 v1 = *(const f16x2*)(cur + (size_t)s1 * H + lane * 2);
            f16x2 v2 = *(const f16x2*)(cur + (size_t)s2 * H + lane * 2);
            f16x2 v3 = *(const f16x2*)(cur + (size_t)s3 * H + lane * 2);
            f16x2 v4 = *(const f16x2*)(cur + (size_t)s4 * H + lane * 2);
            f16x2 v5 = *(const f16x2*)(cur + (size_t)s5 * H + lane * 2);
            f16x2 v6 = *(const f16x2*)(cur + (size_t)s6 * H + lane * 2);
            f16x2 v7 = *(const f16x2*)(cur + (size_t)s7 * H + lane * 2);
            accA += v0; accB += v1; accA += v2; accB += v3;
            accA += v4; accB += v5; accA += v6; accB += v7;
        }
        if (cnt - j >= 4) {
            int s0 = __builtin_amdgcn_readlane(myidx, j + 0);
            int s1 = __builtin_amdgcn_readlane(myidx, j + 1);
            int s2 = __builtin_amdgcn_readlane(myidx, j + 2);
            int s3 = __builtin_amdgcn_readlane(myidx, j + 3);
            f16x2 v0 = *(const f16x2*)(cur + (size_t)s0 * H + lane * 2);
            f16x2 v1 = *(const f16x2*)(cur + (size_t)s1 * H + lane * 2);
            f16x2 v2 = *(const f16x2*)(cur + (size_t)s2 * H + lane * 2);
            f16x2 v3 = *(const f16x2*)(cur + (size_t)s3 * H + lane * 2);
            accA += v0; accB += v1; accA += v2; accB += v3;
            j += 4;
        }
        int rem = cnt - j;
        if (rem > 0) {
            int s0 = __builtin_amdgcn_readlane(myidx, j);
            int s1 = __builtin_amdgcn_readlane(myidx, min(j + 1, cnt - 1));
            int s2 = __builtin_amdgcn_readlane(myidx, min(j + 2, cnt - 1));
            f16x2 v0 = *(const f16x2*)(cur + (size_t)s0 * H + lane * 2);
            f16x2 v1 = *(const f16x2*)(cur + (size_t)s1 * H + lane * 2);
            f16x2 v2 = *(const f16x2*)(cur + (size_t)s2 * H + lane * 2);
            accA += v0;
            if (rem > 1) accB += v1;
            if (rem > 2) accA += v2;
        }
    }
    f16x2 o = accA + accB;
    *(f16x2*)(xaggh + (size_t)node * H + lane * 2) = o;
}

__device__ __forceinline__ void conv_tile(const half_t* cur, const half_t* xaggh,
        const half_t* WtTf, const float* bias, half_t* nxt,
        int n0, int lane, int q, int m, int N) {
    f32x4 acc[8];
#pragma unroll
    for (int ct = 0; ct < 8; ++ct) acc[ct] = (f32x4){0.f, 0.f, 0.f, 0.f};
    int arow = min(n0 + m, N - 1);
#pragma unroll
    for (int s = 0; s < 8; ++s) {
        f16x8 afrag = (s < 4)
            ? *(const f16x8*)(cur   + (size_t)arow * H + s * 32 + q * 8)
            : *(const f16x8*)(xaggh + (size_t)arow * H + (s - 4) * 32 + q * 8);
#pragma unroll
        for (int ct = 0; ct < 8; ++ct) {
            f16x8 bfrag = *(const f16x8*)(WtTf + ((s * 8 + ct) * 64 + lane) * 8);
            acc[ct] = __builtin_amdgcn_mfma_f32_16x16x32_f16(afrag, bfrag, acc[ct], 0, 0, 0);
        }
    }
    float4 b0 = *(const float4*)(bias + m * 8);
    float4 b1 = *(const float4*)(bias + m * 8 + 4);
    float bb[8] = {b0.x, b0.y, b0.z, b0.w, b1.x, b1.y, b1.z, b1.w};
#pragma unroll
    for (int r = 0; r < 4; ++r) {
        int row = n0 + q * 4 + r;
        if (row < N) {
            f16x8 xr = *(const f16x8*)(cur + (size_t)row * H + m * 8);
            f16x8 o;
#pragma unroll
            for (int ct = 0; ct < 8; ++ct) {
                float c = acc[ct][r] + bb[ct];
                o[ct] = (half_t)((float)xr[ct] + EPS * fast_tanh(c));
            }
            *(f16x8*)(nxt + (size_t)row * H + m * 8) = o;
        }
    }
}

__device__ __forceinline__ void prep_body(int i, const float* W, const float* lin_w,
        half_t* WtTf, const float* x0, half_t* xhA, int* deg, int n4, int N) {
    if (i < n4) {
        float4 v = *(const float4*)(x0 + (size_t)i * 4);
        half_t* o = xhA + (size_t)i * 4;
        o[0] = (half_t)v.x; o[1] = (half_t)v.y; o[2] = (half_t)v.z; o[3] = (half_t)v.w;
    }
    if (i < 32768) {
        int t = i & 7;
        int lane = (i >> 3) & 63;
        int ct = (i >> 9) & 7;
        int s = i >> 12;
        int q = lane >> 4, m = lane & 15;
        int j = m * 8 + ct;                  // permuted col mapping
        int k = s * 32 + q * 8 + t;
        float v;
        if (k < H) v = W[j * H + k] - W[k * H + j] - (j == k ? GAMMA : 0.f);
        else       v = lin_w[j * H + (k - H)];
        WtTf[i] = (half_t)v;
    }
    if (i < N) deg[i] = 0;
}

// ================= MEGA cooperative kernel =================
__global__ __launch_bounds__(256, 2) void mega(
        const float* __restrict__ W, const float* __restrict__ lin_w,
        const float* __restrict__ x0, const int* __restrict__ src,
        const int* __restrict__ dst, half_t* __restrict__ WtTf,
        half_t* __restrict__ xhA, half_t* __restrict__ xhB,
        half_t* __restrict__ xaggh, int* __restrict__ deg,
        int* __restrict__ row_start, int* __restrict__ cursor,
        int* __restrict__ csr_src, int* __restrict__ partials,
        int* __restrict__ blkoff, const float* __restrict__ bias,
        int N, int E, int n4) {
    cg::grid_group grid = cg::this_grid();
    __shared__ int sdata[256];
    int tid = threadIdx.x;
    int gtid = blockIdx.x * 256 + tid;
    int gstride = GRID * 256;

    // ---- phase 0: prep + cast + deg=0
    int tot = max(n4, max(32768, N));
    for (int i = gtid; i < tot; i += gstride)
        prep_body(i, W, lin_w, WtTf, x0, xhA, deg, n4, N);
    __threadfence();
    grid.sync();

    // ---- phase 1: in-degree count
    for (int e = gtid; e < E; e += gstride) atomicAdd(&deg[dst[e]], 1);
    __threadfence();
    grid.sync();

    // ---- phase 2a: block-local exclusive scan (chunk <= 256)
    int chunk = (N + GRID - 1) / GRID;
    int base = blockIdx.x * chunk;
    int v0 = 0;
    if (tid < chunk && base + tid < N) v0 = deg[base + tid];
    sdata[tid] = v0;
    __syncthreads();
    for (int off = 1; off < 256; off <<= 1) {
        int u = (tid >= off) ? sdata[tid - off] : 0;
        __syncthreads();
        sdata[tid] += u;
        __syncthreads();
    }
    if (tid < chunk && base + tid < N) row_start[base + tid] = sdata[tid] - v0;
    if (tid == 255) partials[blockIdx.x] = sdata[255];
    __threadfence();
    grid.sync();

    // ---- phase 2b: block 0 scans the 512 partials -> blkoff
    if (blockIdx.x == 0) {
        int p0 = partials[2 * tid], p1 = partials[2 * tid + 1];
        int s = p0 + p1;
        sdata[tid] = s;
        __syncthreads();
        for (int off = 1; off < 256; off <<= 1) {
            int u = (tid >= off) ? sdata[tid - off] : 0;
            __syncthreads();
            sdata[tid] += u;
            __syncthreads();
        }
        int off = sdata[tid] - s;
        blkoff[2 * tid] = off;
        blkoff[2 * tid + 1] = off + p0;
    }
    __threadfence();
    grid.sync();

    // ---- phase 2c: apply block offsets
    int bo = blkoff[blockIdx.x];
    if (tid < chunk && base + tid < N) {
        int r = row_start[base + tid] + bo;
        row_start[base + tid] = r;
        cursor[base + tid] = r;
    }
    if (blockIdx.x == 0 && tid == 0) row_start[N] = E;
    __threadfence();
    grid.sync();

    // ---- phase 3: bucket fill
    for (int e = gtid; e < E; e += gstride) {
        int p = atomicAdd(&cursor[dst[e]], 1);
        csr_src[p] = src[e];
    }
    __threadfence();
    grid.sync();

    // ---- phase 4: 5 iterations of gather + conv
    int wid = __builtin_amdgcn_readfirstlane(blockIdx.x * 4 + (tid >> 6));
    int nwaves = GRID * 4;
    int lane = tid & 63;
    int q = lane >> 4, m = lane & 15;
    int ntiles = (N + 15) / 16;
    half_t* cur = xhA;
    half_t* nxt = xhB;

    for (int it = 0; it < 5; ++it) {
        for (int node = wid; node < N; node += nwaves)
            gather_node(cur, row_start, csr_src, xaggh, node, lane);
        __threadfence();
        grid.sync();

        for (int tix = wid; tix < ntiles; tix += nwaves)
            conv_tile(cur, xaggh, WtTf, bias, nxt, tix * 16, lane, q, m, N);
        __threadfence();
        grid.sync();

        half_t* tmp = cur; cur = nxt; nxt = tmp;
    }
}

// ================= FALLBACK kernels (R14 path, same bodies) =================
__global__ __launch_bounds__(256) void prep_cast_zero(
        const float* __restrict__ W, const float* __restrict__ lin_w,
        half_t* __restrict__ WtTf, const float* __restrict__ x,
        half_t* __restrict__ xh, int n4, int* __restrict__ deg, int N) {
    int stride = gridDim.x * 256;
    int tot = max(n4, max(32768, N));
    for (int i = blockIdx.x * 256 + threadIdx.x; i < tot; i += stride)
        prep_body(i, W, lin_w, WtTf, x, xh, deg, n4, N);
}

__global__ __launch_bounds__(256) void count_kernel(const int* __restrict__ dst,
                                                    int* __restrict__ deg, int E) {
    int stride = gridDim.x * 256;
    for (int e = blockIdx.x * 256 + threadIdx.x; e < E; e += stride)
        atomicAdd(&deg[dst[e]], 1);
}

#define SCHUNK 2048
__global__ __launch_bounds__(256) void scan_part(const int* __restrict__ deg,
                                                 int* __restrict__ partials, int N) {
    __shared__ int red[256];
    int t = threadIdx.x, b = blockIdx.x;
    int base = b * SCHUNK + t * 8;
    int s = 0;
#pragma unroll
    for (int i = 0; i < 8; ++i) { int idx = base + i; if (idx < N) s += deg[idx]; }
    red[t] = s;
    __syncthreads();
    for (int off = 128; off > 0; off >>= 1) {
        if (t < off) red[t] += red[t + off];
        __syncthreads();
    }
    if (t == 0) partials[b] = red[0];
}

__global__ void scan_mid(const int* __restrict__ partials, int* __restrict__ blkoff, int nblk) {
    int lane = threadIdx.x;   // 64 threads
    int p = (lane < nblk) ? partials[lane] : 0;
    int v = p;
    for (int off = 1; off < 64; off <<= 1) {
        int u = __shfl_up(v, off);
        if (lane >= off) v += u;
    }
    if (lane < nblk) blkoff[lane] = v - p;
}

__global__ __launch_bounds__(256) void scan_final(const int* __restrict__ deg,
        const int* __restrict__ blkoff, int* __restrict__ row_start,
        int* __restrict__ cursor, int N, int E) {
    __shared__ int red[256];
    int t = threadIdx.x, b = blockIdx.x;
    int base = b * SCHUNK + t * 8;
    int v[8]; int s = 0;
#pragma unroll
    for (int i = 0; i < 8; ++i) { int idx = base + i; v[i] = (idx < N) ? deg[idx] : 0; s += v[i]; }
    red[t] = s;
    __syncthreads();
    for (int off = 1; off < 256; off <<= 1) {
        int u = (t >= off) ? red[t - off] : 0;
        __syncthreads();
        red[t] += u;
        __syncthreads();
    }
    int run = blkoff[b] + red[t] - s;
#pragma unroll
    for (int i = 0; i < 8; ++i) {
        int idx = base + i;
        if (idx < N) { row_start[idx] = run; cursor[idx] = run; run += v[i]; }
    }
    if (b == 0 && t == 0) row_start[N] = E;
}

__global__ __launch_bounds__(256) void fill_kernel(const int* __restrict__ src,
        const int* __restrict__ dst, int* __restrict__ cursor,
        int* __restrict__ csr_src, int E) {
    int stride = gridDim.x * 256;
    for (int e = blockIdx.x * 256 + threadIdx.x; e < E; e += stride) {
        int p = atomicAdd(&cursor[dst[e]], 1);
        csr_src[p] = src[e];
    }
}

__global__ __launch_bounds__(256) void gather_agg(const half_t* __restrict__ xh,
        const int* __restrict__ row_start, const int* __restrict__ csr_src,
        half_t* __restrict__ xaggh, int N) {
    int wid = __builtin_amdgcn_readfirstlane(blockIdx.x * 4 + (threadIdx.x >> 6));
    int nwaves = gridDim.x * 4;
    int lane = threadIdx.x & 63;
    for (int node = wid; node < N; node += nwaves)
        gather_node(xh, row_start, csr_src, xaggh, node, lane);
}

#define CROWS 64
__global__ __launch_bounds__(256) void conv_mfma(
        const half_t* __restrict__ xh, const half_t* __restrict__ xaggh,
        const half_t* __restrict__ WtTf, const float* __restrict__ bias,
        half_t* __restrict__ xhout, int N) {
    int tid = threadIdx.x;
    int wave = tid >> 6, lane = tid & 63;
    int q = lane >> 4, m = lane & 15;
    int n0 = blockIdx.x * CROWS + wave * 16;
    conv_tile(xh, xaggh, WtTf, bias, xhout, n0, lane, q, m, N);
}

// ---------------- fused triple pooling + 2-layer MLP (one block per graph)
__global__ __launch_bounds__(1024) void pool_mlp(const half_t* __restrict__ x,
        const int* __restrict__ batch,
        const float* __restrict__ l1_w, const float* __restrict__ l1_b,
        const float* __restrict__ l2_w, const float* __restrict__ l2_b,
        float* __restrict__ out, int N) {
    __shared__ float ssum[8][128];
    __shared__ float smax[8][128];
    __shared__ __align__(16) float sp[384];
    __shared__ __align__(16) float sh[192];
    int g = blockIdx.x, t = threadIdx.x;
    int feat = t & 127, slot = t >> 7;
    int lo = 0, hi = N;
    while (lo < hi) { int mid = (lo + hi) >> 1; if (batch[mid] < g) lo = mid + 1; else hi = mid; }
    int start = lo;
    hi = N;
    while (lo < hi) { int mid = (lo + hi) >> 1; if (batch[mid] < g + 1) lo = mid + 1; else hi = mid; }
    int end = lo;
    float sum = 0.f, mx = -INFINITY;
    for (int n = start + slot; n < end; n += 8) {
        float v = (float)x[(size_t)n * H + feat];
        sum += v;
        mx = fmaxf(mx, v);
    }
    ssum[slot][feat] = sum;
    smax[slot][feat] = mx;
    __syncthreads();
    if (t < 128) {
        float s = 0.f, m = -INFINITY;
#pragma unroll
        for (int k = 0; k < 8; ++k) { s += ssum[k][t]; m = fmaxf(m, smax[k][t]); }
        int cnt = end - start;
        sp[t] = s;
        sp[128 + t] = (cnt > 0) ? m : 0.f;
        sp[256 + t] = s / (float)(cnt > 0 ? cnt : 1);
    }
    __syncthreads();
    if (t < 192) {
        float acc = l1_b[t];
        const float* wr = l1_w + (size_t)t * 384;
        for (int k = 0; k < 384; k += 4) {
            float4 w = *(const float4*)(wr + k);
            float4 p = *(const float4*)(sp + k);
            acc += w.x * p.x + w.y * p.y + w.z * p.z + w.w * p.w;
        }
        sh[t] = acc > 0.f ? acc : NEG * acc;
    }
    __syncthreads();
    if (t < 64) {
        float acc = l2_b[t];
        const float* wr = l2_w + (size_t)t * 192;
        for (int k = 0; k < 192; k += 4) {
            float4 w = *(const float4*)(wr + k);
            float4 p = *(const float4*)(sh + k);
            acc += w.x * p.x + w.y * p.y + w.z * p.z + w.w * p.w;
        }
        out[g * 64 + t] = acc > 0.f ? acc : NEG * acc;
    }
}

extern "C" void kernel_launch(void* const* d_in, const int* in_sizes, int n_in,
                              void* d_out, int out_size, void* d_ws, size_t ws_size,
                              hipStream_t stream) {
    const float* x0    = (const float*)d_in[0];
    const int*   edge  = (const int*)d_in[1];
    const int*   batch = (const int*)d_in[2];
    const float* W     = (const float*)d_in[3];
    const float* bias  = (const float*)d_in[4];
    const float* lin_w = (const float*)d_in[5];
    const float* l1_w  = (const float*)d_in[6];
    const float* l1_b  = (const float*)d_in[7];
    const float* l2_w  = (const float*)d_in[8];
    const float* l2_b  = (const float*)d_in[9];
    float* out = (float*)d_out;

    int N = in_sizes[0] / H;
    int E = in_sizes[1] / 2;
    const int* srcp = edge;
    const int* dstp = edge + E;

    size_t nh = (size_t)N * H;
    half_t* xhA    = (half_t*)d_ws;
    half_t* xhB    = xhA + nh;
    half_t* xaggh  = xhB + nh;
    half_t* WtTf   = xaggh + nh;              // 32768 halfs
    int* deg       = (int*)(WtTf + 32768);
    int* row_start = deg + N;                 // N+1
    int* cursor    = row_start + N + 1;
    int* csr_src   = cursor + N;              // E
    int* partials  = csr_src + E;             // 512
    int* blkoff    = partials + 512;          // 512

    int n4 = (int)(nh / 4);

    void* args[] = {
        (void*)&W, (void*)&lin_w, (void*)&x0, (void*)&srcp, (void*)&dstp,
        (void*)&WtTf, (void*)&xhA, (void*)&xhB, (void*)&xaggh, (void*)&deg,
        (void*)&row_start, (void*)&cursor, (void*)&csr_src, (void*)&partials,
        (void*)&blkoff, (void*)&bias, (void*)&N, (void*)&E, (void*)&n4,
    };
    hipError_t cerr = hipLaunchCooperativeKernel((void*)mega, dim3(GRID), dim3(256),
                                                 args, 0, stream);
    if (cerr != hipSuccess) {
        // ---- FALLBACK: proven R14 multi-kernel path (identical math) ----
        prep_cast_zero<<<1024, 256, 0, stream>>>(W, lin_w, WtTf, x0, xhA, n4, deg, N);
        count_kernel<<<1024, 256, 0, stream>>>(dstp, deg, E);
        int nblk = (N + SCHUNK - 1) / SCHUNK;
        scan_part<<<nblk, 256, 0, stream>>>(deg, partials, N);
        scan_mid<<<1, 64, 0, stream>>>(partials, blkoff, nblk);
        scan_final<<<nblk, 256, 0, stream>>>(deg, blkoff, row_start, cursor, N, E);
        fill_kernel<<<1024, 256, 0, stream>>>(srcp, dstp, cursor, csr_src, E);

        const half_t* xcur_h = xhA;
        int nblocks = (N + CROWS - 1) / CROWS;
        for (int it = 0; it < 5; ++it) {
            gather_agg<<<2048, 256, 0, stream>>>(xcur_h, row_start, csr_src, xaggh, N);
            half_t* xnext_h = (it & 1) ? xhA : xhB;
            conv_mfma<<<nblocks, 256, 0, stream>>>(xcur_h, xaggh, WtTf, bias, xnext_h, N);
            xcur_h = xnext_h;
        }
    }

    // after 5 iterations (odd number of swaps), final state is xhB on both paths
    pool_mlp<<<NGRAPH, 1024, 0, stream>>>(xhB, batch, l1_w, l1_b, l2_w, l2_b, out, N);
}

// Round 17
// 378.411 us; speedup vs baseline: 5.7604x; 5.7604x over previous
//
#include <hip/hip_runtime.h>
#include <hip/hip_fp16.h>
#include <cmath>

#define H 128
#define GAMMA 0.1f
#define EPS 0.1f
#define NEG 0.01f
#define NGRAPH 256

typedef _Float16 half_t;
typedef _Float16 f16x8 __attribute__((ext_vector_type(8)));
typedef _Float16 f16x2 __attribute__((ext_vector_type(2)));
typedef float f32x4 __attribute__((ext_vector_type(4)));

__device__ __forceinline__ float fast_tanh(float v) {
    float e = __builtin_amdgcn_exp2f(v * 2.8853900817779268f);
    float r = __builtin_amdgcn_rcpf(e + 1.0f);
    return 1.0f - 2.0f * r;
}

// ---------------- fused (grid-stride): weights->fragment order, x0->f16, deg=0
// Permuted B-frag order: tile ct covers cols j=(lane&15)*8+ct so the MFMA
// C-layout gives each lane 8 consecutive output cols (vector epilogue).
__global__ __launch_bounds__(256) void prep_cast_zero(
        const float* __restrict__ W, const float* __restrict__ lin_w,
        half_t* __restrict__ WtTf, const float* __restrict__ x,
        half_t* __restrict__ xh, int n4, int* __restrict__ deg, int N) {
    int stride = gridDim.x * 256;
    int tot = max(n4, max(32768, N));
    for (int i = blockIdx.x * 256 + threadIdx.x; i < tot; i += stride) {
        if (i < n4) {
            float4 v = *(const float4*)(x + (size_t)i * 4);
            half_t* o = xh + (size_t)i * 4;
            o[0] = (half_t)v.x; o[1] = (half_t)v.y; o[2] = (half_t)v.z; o[3] = (half_t)v.w;
        }
        if (i < 32768) {
            int t = i & 7;
            int lane = (i >> 3) & 63;
            int ct = (i >> 9) & 7;
            int s = i >> 12;
            int q = lane >> 4, m = lane & 15;
            int j = m * 8 + ct;                  // permuted col mapping
            int k = s * 32 + q * 8 + t;
            float v;
            if (k < H) v = W[j * H + k] - W[k * H + j] - (j == k ? GAMMA : 0.f);
            else       v = lin_w[j * H + (k - H)];
            WtTf[i] = (half_t)v;
        }
        if (i < N) deg[i] = 0;
    }
}

// ---------------- CSR build (grid-stride)
__global__ __launch_bounds__(256) void count_kernel(const int* __restrict__ dst,
                                                    int* __restrict__ deg, int E) {
    int stride = gridDim.x * 256;
    for (int e = blockIdx.x * 256 + threadIdx.x; e < E; e += stride)
        atomicAdd(&deg[dst[e]], 1);
}

#define SCHUNK 2048
__global__ __launch_bounds__(256) void scan_part(const int* __restrict__ deg,
                                                 int* __restrict__ partials, int N) {
    __shared__ int red[256];
    int t = threadIdx.x, b = blockIdx.x;
    int base = b * SCHUNK + t * 8;
    int s = 0;
#pragma unroll
    for (int i = 0; i < 8; ++i) { int idx = base + i; if (idx < N) s += deg[idx]; }
    red[t] = s;
    __syncthreads();
    for (int off = 128; off > 0; off >>= 1) {
        if (t < off) red[t] += red[t + off];
        __syncthreads();
    }
    if (t == 0) partials[b] = red[0];
}

// scan_final with scan_mid folded in: wave 0 scans the <=64 partials in-register
// (shfl_up) and broadcasts this block's exclusive offset via LDS.
__global__ __launch_bounds__(256) void scan_final(const int* __restrict__ deg,
        const int* __restrict__ partials, int* __restrict__ row_start,
        int* __restrict__ cursor, int N, int E, int nblk) {
    __shared__ int red[256];
    __shared__ int s_bo;
    int t = threadIdx.x, b = blockIdx.x;
    if (t < 64) {                                // wave 0, fully active
        int p = (t < nblk) ? partials[t] : 0;
        int v = p;
        for (int off = 1; off < 64; off <<= 1) {
            int u = __shfl_up(v, off);
            if (t >= off) v += u;
        }
        int bo = (b == 0) ? 0 : __shfl(v, b - 1);  // inclusive[b-1] = exclusive[b]
        if (t == 0) s_bo = bo;
    }
    int base = b * SCHUNK + t * 8;
    int v[8]; int s = 0;
#pragma unroll
    for (int i = 0; i < 8; ++i) { int idx = base + i; v[i] = (idx < N) ? deg[idx] : 0; s += v[i]; }
    red[t] = s;
    __syncthreads();
    for (int off = 1; off < 256; off <<= 1) {
        int u = (t >= off) ? red[t - off] : 0;
        __syncthreads();
        red[t] += u;
        __syncthreads();
    }
    int run = s_bo + red[t] - s;
#pragma unroll
    for (int i = 0; i < 8; ++i) {
        int idx = base + i;
        if (idx < N) { row_start[idx] = run; cursor[idx] = run; run += v[i]; }
    }
    if (b == 0 && t == 0) row_start[N] = E;
}

__global__ __launch_bounds__(256) void fill_kernel(const int* __restrict__ src,
        const int* __restrict__ dst, int* __restrict__ cursor,
        int* __restrict__ csr_src, int E) {
    int stride = gridDim.x * 256;
    for (int e = blockIdx.x * 256 + threadIdx.x; e < E; e += stride) {
        int p = atomicAdd(&cursor[dst[e]], 1);
        csr_src[p] = src[e];
    }
}

// ---------------- gather aggregation (R12/R14-proven): per-wave stride over
// nodes; scalar-uniform control; v_readlane edge indices; packed-f16 accum.
__global__ __launch_bounds__(256) void gather_agg(const half_t* __restrict__ xh,
        const int* __restrict__ row_start, const int* __restrict__ csr_src,
        half_t* __restrict__ xaggh, int N) {
    int wid = __builtin_amdgcn_readfirstlane(blockIdx.x * 4 + (threadIdx.x >> 6));
    int nwaves = gridDim.x * 4;
    int lane = threadIdx.x & 63;
    for (int node = wid; node < N; node += nwaves) {
        int begin = row_start[node];
        int end   = row_start[node + 1];
        f16x2 accA = (f16x2){(half_t)0.f, (half_t)0.f};
        f16x2 accB = (f16x2){(half_t)0.f, (half_t)0.f};
        for (int eb = begin; eb < end; eb += 64) {
            int cnt = min(64, end - eb);
            int myidx = csr_src[eb + min(lane, cnt - 1)];
            int j = 0;
            for (; j + 7 < cnt; j += 8) {
                int s0 = __builtin_amdgcn_readlane(myidx, j + 0);
                int s1 = __builtin_amdgcn_readlane(myidx, j + 1);
                int s2 = __builtin_amdgcn_readlane(myidx, j + 2);
                int s3 = __builtin_amdgcn_readlane(myidx, j + 3);
                int s4 = __builtin_amdgcn_readlane(myidx, j + 4);
                int s5 = __builtin_amdgcn_readlane(myidx, j + 5);
                int s6 = __builtin_amdgcn_readlane(myidx, j + 6);
                int s7 = __builtin_amdgcn_readlane(myidx, j + 7);
                f16x2 v0 = *(const f16x2*)(xh + (size_t)s0 * H + lane * 2);
                f16x2 v1 = *(const f16x2*)(xh + (size_t)s1 * H + lane * 2);
                f16x2 v2 = *(const f16x2*)(xh + (size_t)s2 * H + lane * 2);
                f16x2 v3 = *(const f16x2*)(xh + (size_t)s3 * H + lane * 2);
                f16x2 v4 = *(const f16x2*)(xh + (size_t)s4 * H + lane * 2);
                f16x2 v5 = *(const f16x2*)(xh + (size_t)s5 * H + lane * 2);
                f16x2 v6 = *(const f16x2*)(xh + (size_t)s6 * H + lane * 2);
                f16x2 v7 = *(const f16x2*)(xh + (size_t)s7 * H + lane * 2);
                accA += v0; accB += v1; accA += v2; accB += v3;
                accA += v4; accB += v5; accA += v6; accB += v7;
            }
            if (cnt - j >= 4) {
                int s0 = __builtin_amdgcn_readlane(myidx, j + 0);
                int s1 = __builtin_amdgcn_readlane(myidx, j + 1);
                int s2 = __builtin_amdgcn_readlane(myidx, j + 2);
                int s3 = __builtin_amdgcn_readlane(myidx, j + 3);
                f16x2 v0 = *(const f16x2*)(xh + (size_t)s0 * H + lane * 2);
                f16x2 v1 = *(const f16x2*)(xh + (size_t)s1 * H + lane * 2);
                f16x2 v2 = *(const f16x2*)(xh + (size_t)s2 * H + lane * 2);
                f16x2 v3 = *(const f16x2*)(xh + (size_t)s3 * H + lane * 2);
                accA += v0; accB += v1; accA += v2; accB += v3;
                j += 4;
            }
            int rem = cnt - j;
            if (rem > 0) {
                int s0 = __builtin_amdgcn_readlane(myidx, j);
                int s1 = __builtin_amdgcn_readlane(myidx, min(j + 1, cnt - 1));
                int s2 = __builtin_amdgcn_readlane(myidx, min(j + 2, cnt - 1));
                f16x2 v0 = *(const f16x2*)(xh + (size_t)s0 * H + lane * 2);
                f16x2 v1 = *(const f16x2*)(xh + (size_t)s1 * H + lane * 2);
                f16x2 v2 = *(const f16x2*)(xh + (size_t)s2 * H + lane * 2);
                accA += v0;
                if (rem > 1) accB += v1;
                if (rem > 2) accA += v2;
            }
        }
        f16x2 o = accA + accB;
        *(f16x2*)(xaggh + (size_t)node * H + lane * 2) = o;
    }
}

// ---------------- conv+update (R14-proven): 4 waves x 16 rows = 64 rows/block,
// acc[8] only; permuted B layout -> f16x8 vector residual load + store.
#define CROWS 64
__global__ __launch_bounds__(256) void conv_mfma(
        const half_t* __restrict__ xh, const half_t* __restrict__ xaggh,
        const half_t* __restrict__ WtTf, const float* __restrict__ bias,
        half_t* __restrict__ xhout, int N) {
    int tid = threadIdx.x;
    int wave = tid >> 6, lane = tid & 63;
    int q = lane >> 4, m = lane & 15;
    int n0 = blockIdx.x * CROWS + wave * 16;

    f32x4 acc[8];
#pragma unroll
    for (int ct = 0; ct < 8; ++ct) acc[ct] = (f32x4){0.f, 0.f, 0.f, 0.f};

    int arow = min(n0 + m, N - 1);
#pragma unroll
    for (int s = 0; s < 8; ++s) {
        f16x8 afrag = (s < 4)
            ? *(const f16x8*)(xh    + (size_t)arow * H + s * 32 + q * 8)
            : *(const f16x8*)(xaggh + (size_t)arow * H + (s - 4) * 32 + q * 8);
#pragma unroll
        for (int ct = 0; ct < 8; ++ct) {
            f16x8 bfrag = *(const f16x8*)(WtTf + ((s * 8 + ct) * 64 + lane) * 8);
            acc[ct] = __builtin_amdgcn_mfma_f32_16x16x32_f16(afrag, bfrag, acc[ct], 0, 0, 0);
        }
    }

    float4 b0 = *(const float4*)(bias + m * 8);
    float4 b1 = *(const float4*)(bias + m * 8 + 4);
    float bb[8] = {b0.x, b0.y, b0.z, b0.w, b1.x, b1.y, b1.z, b1.w};
#pragma unroll
    for (int r = 0; r < 4; ++r) {
        int row = n0 + q * 4 + r;
        if (row < N) {
            f16x8 xr = *(const f16x8*)(xh + (size_t)row * H + m * 8);
            f16x8 o;
#pragma unroll
            for (int ct = 0; ct < 8; ++ct) {
                float c = acc[ct][r] + bb[ct];
                o[ct] = (half_t)((float)xr[ct] + EPS * fast_tanh(c));
            }
            *(f16x8*)(xhout + (size_t)row * H + m * 8) = o;
        }
    }
}

// ---------------- fused triple pooling + 2-layer MLP (one block per graph)
__global__ __launch_bounds__(1024) void pool_mlp(const half_t* __restrict__ x,
        const int* __restrict__ batch,
        const float* __restrict__ l1_w, const float* __restrict__ l1_b,
        const float* __restrict__ l2_w, const float* __restrict__ l2_b,
        float* __restrict__ out, int N) {
    __shared__ float ssum[8][128];
    __shared__ float smax[8][128];
    __shared__ __align__(16) float sp[384];
    __shared__ __align__(16) float sh[192];
    int g = blockIdx.x, t = threadIdx.x;
    int feat = t & 127, slot = t >> 7;
    int lo = 0, hi = N;
    while (lo < hi) { int mid = (lo + hi) >> 1; if (batch[mid] < g) lo = mid + 1; else hi = mid; }
    int start = lo;
    hi = N;
    while (lo < hi) { int mid = (lo + hi) >> 1; if (batch[mid] < g + 1) lo = mid + 1; else hi = mid; }
    int end = lo;
    float sum = 0.f, mx = -INFINITY;
    for (int n = start + slot; n < end; n += 8) {
        float v = (float)x[(size_t)n * H + feat];
        sum += v;
        mx = fmaxf(mx, v);
    }
    ssum[slot][feat] = sum;
    smax[slot][feat] = mx;
    __syncthreads();
    if (t < 128) {
        float s = 0.f, m = -INFINITY;
#pragma unroll
        for (int k = 0; k < 8; ++k) { s += ssum[k][t]; m = fmaxf(m, smax[k][t]); }
        int cnt = end - start;
        sp[t] = s;
        sp[128 + t] = (cnt > 0) ? m : 0.f;
        sp[256 + t] = s / (float)(cnt > 0 ? cnt : 1);
    }
    __syncthreads();
    if (t < 192) {
        float acc = l1_b[t];
        const float* wr = l1_w + (size_t)t * 384;
        for (int k = 0; k < 384; k += 4) {
            float4 w = *(const float4*)(wr + k);
            float4 p = *(const float4*)(sp + k);
            acc += w.x * p.x + w.y * p.y + w.z * p.z + w.w * p.w;
        }
        sh[t] = acc > 0.f ? acc : NEG * acc;
    }
    __syncthreads();
    if (t < 64) {
        float acc = l2_b[t];
        const float* wr = l2_w + (size_t)t * 192;
        for (int k = 0; k < 192; k += 4) {
            float4 w = *(const float4*)(wr + k);
            float4 p = *(const float4*)(sh + k);
            acc += w.x * p.x + w.y * p.y + w.z * p.z + w.w * p.w;
        }
        out[g * 64 + t] = acc > 0.f ? acc : NEG * acc;
    }
}

extern "C" void kernel_launch(void* const* d_in, const int* in_sizes, int n_in,
                              void* d_out, int out_size, void* d_ws, size_t ws_size,
                              hipStream_t stream) {
    const float* x0    = (const float*)d_in[0];
    const int*   edge  = (const int*)d_in[1];
    const int*   batch = (const int*)d_in[2];
    const float* W     = (const float*)d_in[3];
    const float* bias  = (const float*)d_in[4];
    const float* lin_w = (const float*)d_in[5];
    const float* l1_w  = (const float*)d_in[6];
    const float* l1_b  = (const float*)d_in[7];
    const float* l2_w  = (const float*)d_in[8];
    const float* l2_b  = (const float*)d_in[9];
    float* out = (float*)d_out;

    int N = in_sizes[0] / H;
    int E = in_sizes[1] / 2;
    const int* src = edge;
    const int* dst = edge + E;

    size_t nh = (size_t)N * H;
    half_t* xhA    = (half_t*)d_ws;
    half_t* xhB    = xhA + nh;
    half_t* xaggh  = xhB + nh;
    half_t* WtTf   = xaggh + nh;              // 32768 halfs
    int* deg       = (int*)(WtTf + 32768);
    int* row_start = deg + N;                 // N+1
    int* cursor    = row_start + N + 1;
    int* csr_src   = cursor + N;              // E
    int* partials  = csr_src + E;             // 64

    int n4 = (int)(nh / 4);
    prep_cast_zero<<<1024, 256, 0, stream>>>(W, lin_w, WtTf, x0, xhA, n4, deg, N);

    count_kernel<<<1024, 256, 0, stream>>>(dst, deg, E);
    int nblk = (N + SCHUNK - 1) / SCHUNK;     // 25 for N=50000 (<=64 required)
    scan_part<<<nblk, 256, 0, stream>>>(deg, partials, N);
    scan_final<<<nblk, 256, 0, stream>>>(deg, partials, row_start, cursor, N, E, nblk);
    fill_kernel<<<1024, 256, 0, stream>>>(src, dst, cursor, csr_src, E);

    const half_t* xcur_h = xhA;
    int nblocks = (N + CROWS - 1) / CROWS;
    for (int it = 0; it < 5; ++it) {
        gather_agg<<<2048, 256, 0, stream>>>(xcur_h, row_start, csr_src, xaggh, N);
        half_t* xnext_h = (it & 1) ? xhA : xhB;
        conv_mfma<<<nblocks, 256, 0, stream>>>(xcur_h, xaggh, WtTf, bias, xnext_h, N);
        xcur_h = xnext_h;
    }

    pool_mlp<<<NGRAPH, 1024, 0, stream>>>(xcur_h, batch, l1_w, l1_b, l2_w, l2_b, out, N);
}